// Round 1
// 111.140 us; speedup vs baseline: 1.0905x; 1.0905x over previous
//
#include <hip/hip_runtime.h>
#include <math.h>
#include <float.h>

// b=8, c=64, H=W=64, KS=8 -> P = 57*57 = 3249.
// Stage 1 per (b,c): G[m,n] = <patch_m, patch_n> over P; corr = G/(sqrt(diag)sqrt(diag)P);
//   sort 64 m per column n desc; ranks {1,9,16,24,32,40,48,55,63} -> xp[b,c,576].
// Stage 2 per b: corr2[p,q] = sum_c Xn[c,p]Xn[c,q]/64; sort 576 p per q desc; 115 ranks.
//
// R7: k1 pair-symmetric with DPP scan; canonical upper-triangle G; k3 fused.
// R8: k3 sort reworked from 1024-padded lane-major bitonic (16 regs, 448 pads)
//     to 9-reg reg-major 576 merge-tree (zero padding): 9x sort64 -> merge tree
//     128/256/512 -> non-pow2 final merge (cer(v7,v8) from -inf constant-prop).
//     Loads become stride-1 (kills ds_read_b128 bank conflicts); xor-4/8/16 via
//     immediate ds_swizzle; ipq scale deferred to extracted ranks.

#define IMGS 65

// ---- DPP helpers (compile-time ctrl via templates; LDS-pipe-free cross-lane) ----
template<int CTRL, int RM>
__device__ __forceinline__ float dpp_add(float x) {
    int o = __builtin_amdgcn_update_dpp(0, __float_as_int(x), CTRL, RM, 0xf, true);
    return x + __int_as_float(o);
}
// inclusive wave64 prefix sum: row_shr 1/2/4/8, then bcast15 (rows 1,3), bcast31 (rows 2,3)
__device__ __forceinline__ float wscan_add(float x) {
    x = dpp_add<0x111, 0xf>(x);
    x = dpp_add<0x112, 0xf>(x);
    x = dpp_add<0x114, 0xf>(x);
    x = dpp_add<0x118, 0xf>(x);
    x = dpp_add<0x142, 0xa>(x);
    x = dpp_add<0x143, 0xc>(x);
    return x;
}
template<int CTRL>
__device__ __forceinline__ float dpp_perm(float x) {
    int o = __builtin_amdgcn_update_dpp(__float_as_int(x), __float_as_int(x), CTRL, 0xf, 0xf, false);
    return __int_as_float(o);
}
// xor-1 / xor-2 within quads
#define QP_XOR1 0xB1   // [1,0,3,2]
#define QP_XOR2 0x4E   // [2,3,0,1]

__host__ __device__ constexpr int offF(int dj) { return dj * (17 - dj) / 2; }       // 36 total
__host__ __device__ constexpr int offB(int dj) { return (dj - 1) * (16 - dj) / 2; } // 28 total

// ---------------- k1: fused stage-1, pair-symmetric, canonical-G ----------------
// grid = 512 (bc), block = 512 (8 waves; wave wv handles row-shift d = wv)
__global__ __launch_bounds__(512) void k1(const float* __restrict__ x,
                                          float* __restrict__ xp) {
    __shared__ float img[64 * IMGS];   // 16.6 KB
    __shared__ float G[64 * IMGS];     // canonical: G[m*65+n], m<=n

    const int t = threadIdx.x;
    const int bc = blockIdx.x;
    const float* src = x + (size_t)bc * 4096;

    #pragma unroll
    for (int k = 0; k < 2; ++k) {
        int i4 = t + k * 512;
        float4 v = ((const float4*)src)[i4];
        int fl = i4 * 4, row = fl >> 6, col = fl & 63;
        float* dd = &img[row * IMGS + col];
        dd[0] = v.x; dd[1] = v.y; dd[2] = v.z; dd[3] = v.w;
    }
    __syncthreads();

    const int wv = t >> 6, lane = t & 63;
    const int d = wv;                            // 0..7
    const int a = lane;
    const bool av = (a + d <= 63);
    const int a1 = min(a + d, 63);
    const float* r0 = &img[a * IMGS];
    const float* r1 = &img[a1 * IMGS];

    // ---- FMA phase: wf[k]=sum r0[u]*r1[u+k], wb[k]=sum r1[u]*r0[u+k]  (u=0..56) ----
    float wf[8] = {0,0,0,0,0,0,0,0}, wb[8] = {0,0,0,0,0,0,0,0};
    float sf[8], sb[8], hf[7], hb[7];
    #pragma unroll
    for (int k = 0; k < 7; ++k) { sf[k] = r1[k]; sb[k] = r0[k]; hf[k] = sf[k]; hb[k] = sb[k]; }
    #pragma unroll
    for (int c = 0; c < 7; ++c) {
        #pragma unroll
        for (int j = 0; j < 8; ++j) {
            const int u = c * 8 + j;
            sf[(j + 7) & 7] = r1[u + 7];
            sb[(j + 7) & 7] = r0[u + 7];
            const float f0 = sb[j & 7];          // r0[u]
            const float g0 = sf[j & 7];          // r1[u]
            #pragma unroll
            for (int k = 0; k < 8; ++k) wf[k] = fmaf(f0, sf[(j + k) & 7], wf[k]);
            #pragma unroll
            for (int k = 1; k < 8; ++k) wb[k] = fmaf(g0, sb[(j + k) & 7], wb[k]);
        }
    }
    {   // u = 56 (j-pattern 0)
        sf[7] = r1[63]; sb[7] = r0[63];
        const float f0 = sb[0], g0 = sf[0];
        #pragma unroll
        for (int k = 0; k < 8; ++k) wf[k] = fmaf(f0, sf[k], wf[k]);
        #pragma unroll
        for (int k = 1; k < 8; ++k) wb[k] = fmaf(g0, sb[k], wb[k]);
    }
    // now sf[k] = r1[56+k], sb[k] = r0[56+k]  (tails); hf/hb = heads

    // ---- slide over st (all indices compile-time) ----
    float Wf[36], Wb[28];
    #pragma unroll
    for (int dj = 0; dj < 8; ++dj) {
        float a0 = wf[dj];
        Wf[offF(dj)] = a0;
        #pragma unroll
        for (int st = 1; st < 8 - dj; ++st) {
            a0 += sb[st] * sf[st + dj] - hb[st - 1] * hf[st - 1 + dj];
            Wf[offF(dj) + st] = a0;
        }
    }
    #pragma unroll
    for (int dj = 1; dj < 8; ++dj) {
        float a0 = wb[dj];
        Wb[offB(dj)] = a0;
        #pragma unroll
        for (int st = 1; st < 8 - dj; ++st) {
            a0 += sf[st] * sb[st + dj] - hf[st - 1] * hb[st - 1 + dj];
            Wb[offB(dj) + st] = a0;
        }
    }

    // ---- mask invalid rows, DPP prefix-scan over lanes (rows a) ----
    const float msk = av ? 1.0f : 0.0f;
    #pragma unroll
    for (int i = 0; i < 36; ++i) Wf[i] = wscan_add(Wf[i] * msk);
    if (d > 0) {
        #pragma unroll
        for (int i = 0; i < 28; ++i) Wb[i] = wscan_add(Wb[i] * msk);
    }

    // ---- extract: S(ki) on lane ki+56 = P[lane] - P[lane-57]; write canonical G ----
    const bool wr = (lane >= 56) && (lane <= 63 - d);
    const int ki = lane - 56;
    #pragma unroll
    for (int dj = 0; dj < 8; ++dj) {
        #pragma unroll
        for (int st = 0; st < 8 - dj; ++st) {
            {
                float P = Wf[offF(dj) + st];
                float sl = __shfl_up(P, 57, 64);
                float S = P - (lane >= 57 ? sl : 0.0f);
                if (wr) G[(ki * 8 + st) * IMGS + ((ki + d) * 8 + st + dj)] = S;
            }
            if (d > 0 && dj > 0) {
                float P = Wb[offB(dj) + st];
                float sl = __shfl_up(P, 57, 64);
                float S = P - (lane >= 57 ? sl : 0.0f);
                if (wr) G[(ki * 8 + st + dj) * IMGS + ((ki + d) * 8 + st)] = S;
            }
        }
    }
    __syncthreads();

    // ---- normalize + batched sort64 (wave wv: columns wv*8..wv*8+7) ----
    const int m = lane;
    const float invm = 1.0f / fmaxf(sqrtf(G[m * 66]), 1e-12f);
    const float sc = 1.0f / 3249.0f;
    const int c0 = wv * 8;
    float v[8];
    #pragma unroll
    for (int cc = 0; cc < 8; ++cc) {
        const int col = c0 + cc;
        const int addr = (m <= col) ? m * IMGS + col : col * IMGS + m;   // symmetric read
        const float invc = __shfl(invm, col, 64);
        v[cc] = G[addr] * invm * invc * sc;
    }
    #pragma unroll
    for (int kk = 2; kk <= 64; kk <<= 1) {
        #pragma unroll
        for (int j = kk >> 1; j > 0; j >>= 1) {
            const bool upper = (lane & j) != 0;
            const bool dir0  = (lane & kk) == 0;
            const bool keep_max = dir0 ^ upper;
            float o[8];
            #pragma unroll
            for (int cc = 0; cc < 8; ++cc) {
                if (j == 1)      o[cc] = dpp_perm<QP_XOR1>(v[cc]);
                else if (j == 2) o[cc] = dpp_perm<QP_XOR2>(v[cc]);
                else             o[cc] = __shfl_xor(v[cc], j, 64);
            }
            #pragma unroll
            for (int cc = 0; cc < 8; ++cc)
                v[cc] = keep_max ? fmaxf(v[cc], o[cc]) : fminf(v[cc], o[cc]);
        }
    }
    // ranks2 = {1,9,16,24,32,40,48,55,63}
    int ridx = -1;
    if      (lane ==  1) ridx = 0; else if (lane ==  9) ridx = 1; else if (lane == 16) ridx = 2;
    else if (lane == 24) ridx = 3; else if (lane == 32) ridx = 4; else if (lane == 40) ridx = 5;
    else if (lane == 48) ridx = 6; else if (lane == 55) ridx = 7; else if (lane == 63) ridx = 8;
    if (ridx >= 0) {
        float* dst = xp + (size_t)bc * 576 + ridx * 64 + c0;
        *(float4*)&dst[0] = make_float4(v[0], v[1], v[2], v[3]);
        *(float4*)&dst[4] = make_float4(v[4], v[5], v[6], v[7]);
    }
}

// ---- sort-576 building blocks (reg-major layout: element e = r*64 + lane) ----
template<int J>
__device__ __forceinline__ float shx(float x) {
    if constexpr (J == 1)       return dpp_perm<QP_XOR1>(x);
    else if constexpr (J == 2)  return dpp_perm<QP_XOR2>(x);
    else if constexpr (J <= 16) // immediate ds_swizzle: xor-J within 32-half (bit5 kept)
        return __int_as_float(__builtin_amdgcn_ds_swizzle(__float_as_int(x), (J << 10) | 0x1F));
    else                        return __shfl_xor(x, J, 64);
}

template<int J>
__device__ __forceinline__ void cex(float& v, const bool keep_max) {
    const float o = shx<J>(v);
    v = keep_max ? fmaxf(v, o) : fminf(v, o);
}

// in-lane compare-exchange between two regs; DESC: a (lower position) keeps max
template<int DESC>
__device__ __forceinline__ void cer(float& a, float& b) {
    const float mx = fmaxf(a, b), mn = fminf(a, b);
    if constexpr (DESC) { a = mx; b = mn; } else { a = mn; b = mx; }
}

// bitonic merge of a 64-element bitonic sequence held across lanes in one reg
template<int DESC>
__device__ __forceinline__ void merge64(float& v, const int lane) {
    cex<32>(v, (((lane & 32) != 0) ^ DESC) != 0);
    cex<16>(v, (((lane & 16) != 0) ^ DESC) != 0);
    cex<8>(v,  (((lane &  8) != 0) ^ DESC) != 0);
    cex<4>(v,  (((lane &  4) != 0) ^ DESC) != 0);
    cex<2>(v,  (((lane &  2) != 0) ^ DESC) != 0);
    cex<1>(v,  (((lane &  1) != 0) ^ DESC) != 0);
}

// ---------------- k3: fused stage-2 (Gram columns + norms + sort + ranks) ----------------
// grid = 8*64 (b x q-group of 9), block = 576 (9 waves; wave sorts column q0+wv)
__global__ __launch_bounds__(576) void k3(const float* __restrict__ xp,
                                          float* __restrict__ out) {
    __shared__ __align__(16) float sbuf[9 * 580];   // raw corr columns, stride 580
    __shared__ __align__(16) float ipL[576];        // per-p inverse channel norms
    __shared__ float rankbuf[115 * 12];
    const int t = threadIdx.x;
    const int b = blockIdx.x >> 6, qg = blockIdx.x & 63;
    const int q0 = qg * 9;
    const float* __restrict__ xb = xp + (size_t)b * 36864;

    // ---- phase 1: thread p computes raw corr2 col entries for 9 q's + own norm ----
    {
        const int p = t;
        float acc[9] = {0,0,0,0,0,0,0,0,0};
        float sd = 0.f;
        #pragma unroll 8
        for (int c = 0; c < 64; ++c) {
            const float xv = xb[c * 576 + p];                  // coalesced vector load
            sd = fmaf(xv, xv, sd);
            #pragma unroll
            for (int qq = 0; qq < 9; ++qq)
                acc[qq] = fmaf(xv, xb[c * 576 + q0 + qq], acc[qq]);  // uniform -> s_load
        }
        ipL[p] = 1.0f / fmaxf(sqrtf(sd), 1e-12f);
        #pragma unroll
        for (int qq = 0; qq < 9; ++qq) sbuf[qq * 580 + p] = acc[qq];
    }
    __syncthreads();

    // ---- phase 2: wave wv sorts column q = q0+wv, 9-reg merge-tree (no padding) ----
    const int wv = t >> 6, lane = t & 63;
    const float ipq = ipL[q0 + wv] * 0.015625f;   // /64 ; >0, order-preserving -> deferred
    float v[9];
    {
        const float* sb2 = &sbuf[wv * 580];
        #pragma unroll
        for (int r = 0; r < 9; ++r)
            v[r] = sb2[r * 64 + lane] * ipL[r * 64 + lane];   // stride-1: conflict-free
    }

    // level 0: per-reg 64-sorts; dirs: desc {0,3,5,6}, asc {1,2,4,7,8}
    #define SSTAGE(KK, J) { \
        const bool kma = (((lane & (J)) != 0) == ((lane & (KK)) == 0)); \
        cex<J>(v[0], !kma); cex<J>(v[1],  kma); cex<J>(v[2],  kma); cex<J>(v[3], !kma); \
        cex<J>(v[4],  kma); cex<J>(v[5], !kma); cex<J>(v[6], !kma); cex<J>(v[7],  kma); \
        cex<J>(v[8],  kma); }
    SSTAGE(2, 1)
    SSTAGE(4, 2)   SSTAGE(4, 1)
    SSTAGE(8, 4)   SSTAGE(8, 2)   SSTAGE(8, 1)
    SSTAGE(16, 8)  SSTAGE(16, 4)  SSTAGE(16, 2)  SSTAGE(16, 1)
    SSTAGE(32, 16) SSTAGE(32, 8)  SSTAGE(32, 4)  SSTAGE(32, 2)  SSTAGE(32, 1)
    SSTAGE(64, 32) SSTAGE(64, 16) SSTAGE(64, 8)  SSTAGE(64, 4)  SSTAGE(64, 2) SSTAGE(64, 1)
    #undef SSTAGE

    // level 1: (0,1)->desc128, (2,3)->asc128, (4,5)->asc128, (6,7)->desc128
    cer<1>(v[0], v[1]); cer<0>(v[2], v[3]); cer<0>(v[4], v[5]); cer<1>(v[6], v[7]);
    merge64<1>(v[0], lane); merge64<1>(v[1], lane);
    merge64<0>(v[2], lane); merge64<0>(v[3], lane);
    merge64<0>(v[4], lane); merge64<0>(v[5], lane);
    merge64<1>(v[6], lane); merge64<1>(v[7], lane);

    // level 2: (0-3)->desc256, (4-7)->asc256
    cer<1>(v[0], v[2]); cer<1>(v[1], v[3]);
    cer<1>(v[0], v[1]); cer<1>(v[2], v[3]);
    merge64<1>(v[0], lane); merge64<1>(v[1], lane); merge64<1>(v[2], lane); merge64<1>(v[3], lane);
    cer<0>(v[4], v[6]); cer<0>(v[5], v[7]);
    cer<0>(v[4], v[5]); cer<0>(v[6], v[7]);
    merge64<0>(v[4], lane); merge64<0>(v[5], lane); merge64<0>(v[6], lane); merge64<0>(v[7], lane);

    // level 3: (0-7)->desc512
    cer<1>(v[0], v[4]); cer<1>(v[1], v[5]); cer<1>(v[2], v[6]); cer<1>(v[3], v[7]);
    cer<1>(v[0], v[2]); cer<1>(v[1], v[3]); cer<1>(v[4], v[6]); cer<1>(v[5], v[7]);
    cer<1>(v[0], v[1]); cer<1>(v[2], v[3]); cer<1>(v[4], v[5]); cer<1>(v[6], v[7]);
    #pragma unroll
    for (int r = 0; r < 8; ++r) merge64<1>(v[r], lane);

    // level 4: desc512 + asc64(reg8) -> desc576.
    // Virtual 1024 merge with -inf pads constant-propagated: the only real CE of the
    // j=512 stage pairs positions 448..511 (reg7) with 960..1023 (reg8); reg8's
    // subsequent j=256/128/64 stages are pure renames landing it at positions 512..575.
    cer<1>(v[7], v[8]);
    cer<1>(v[0], v[4]); cer<1>(v[1], v[5]); cer<1>(v[2], v[6]); cer<1>(v[3], v[7]);
    cer<1>(v[0], v[2]); cer<1>(v[1], v[3]); cer<1>(v[4], v[6]); cer<1>(v[5], v[7]);
    cer<1>(v[0], v[1]); cer<1>(v[2], v[3]); cer<1>(v[4], v[5]); cer<1>(v[6], v[7]);
    #pragma unroll
    for (int r = 0; r < 8; ++r) merge64<1>(v[r], lane);
    merge64<1>(v[8], lane);

    // ---- extract ranks = round(linspace(1,575,115)) == 1 + 5i + (2i)/57 + ((2i%57)>=29)
    // sorted descending position of reg r = r*64 + lane (reg8 holds 512..575)
    #pragma unroll
    for (int r = 0; r < 9; ++r) {
        const int pos = r * 64 + lane;
        const int rr0 = (int)((float)pos * 0.1993f);
        #pragma unroll
        for (int dd = -1; dd <= 2; ++dd) {
            const int cand = rr0 + dd;
            if (cand >= 0 && cand < 115) {
                const int ti = 2 * cand;
                const int rk = 1 + 5 * cand + ti / 57 + ((ti % 57) >= 29 ? 1 : 0);
                if (rk == pos) rankbuf[cand * 12 + wv] = v[r] * ipq;
            }
        }
    }
    __syncthreads();
    for (int i = t; i < 115 * 9; i += 576) {
        const int rr = i / 9, qq = i - rr * 9;
        out[(size_t)b * 66240 + rr * 576 + q0 + qq] = rankbuf[rr * 12 + qq];
    }
}

extern "C" void kernel_launch(void* const* d_in, const int* in_sizes, int n_in,
                              void* d_out, int out_size, void* d_ws, size_t ws_size,
                              hipStream_t stream) {
    const float* x = (const float*)d_in[0];   // [8,64,64,64] fp32
    float* out = (float*)d_out;               // [8,115,24,24] fp32
    float* xp = (float*)d_ws;                 // [8,64,576] = 294912 floats (~1.2 MB)

    k1<<<dim3(512), dim3(512), 0, stream>>>(x, xp);
    k3<<<dim3(512), dim3(576), 0, stream>>>(xp, out);
}